// Round 1
// baseline (277.834 us; speedup 1.0000x reference)
//
#include <hip/hip_runtime.h>
#include <stdint.h>
#include <stddef.h>

typedef short bf16x8 __attribute__((ext_vector_type(8)));
typedef float f32x4 __attribute__((ext_vector_type(4)));

#define AS1 __attribute__((address_space(1)))
#define AS3 __attribute__((address_space(3)))

__device__ __forceinline__ unsigned short f2bf(float f) {
    union { float f; uint32_t u; } v; v.f = f;
    return (unsigned short)((v.u + 0x7fffu + ((v.u >> 16) & 1u)) >> 16);
}

// ---------- f32 -> bf16 convert (4 elems/thread) ----------
__global__ void cvt_f32_bf16(const float* __restrict__ in, unsigned short* __restrict__ out, int n4) {
    int i = blockIdx.x * blockDim.x + threadIdx.x;
    if (i >= n4) return;
    float4 v = reinterpret_cast<const float4*>(in)[i];
    ushort4 o;
    o.x = f2bf(v.x); o.y = f2bf(v.y); o.z = f2bf(v.z); o.w = f2bf(v.w);
    reinterpret_cast<ushort4*>(out)[i] = o;
}

// ---------- 512x512 transpose f32 -> bf16 : WT[n][k] = W[k][n] ----------
__global__ void wtrans(const float* __restrict__ W, unsigned short* __restrict__ WT) {
    __shared__ float tile[32][33];
    int bk = blockIdx.x * 32, bn = blockIdx.y * 32;
    int tx = threadIdx.x, ty = threadIdx.y;
#pragma unroll
    for (int r = 0; r < 32; r += 8)
        tile[ty + r][tx] = W[(size_t)(bk + ty + r) * 512 + bn + tx];
    __syncthreads();
#pragma unroll
    for (int r = 0; r < 32; r += 8)
        WT[(size_t)(bn + ty + r) * 512 + bk + tx] = f2bf(tile[tx][ty + r]);
}

// ---------- GEMM: C[M=8192][N=512] = A[M][512](bf16) * BT[N][512](bf16)^T + bias ----------
// EPI 0: K-proj -> kb  [B][H][S][64] bf16
// EPI 1: V-proj -> vT  [B][H][64][S] bf16
// EPI 2: O-proj -> out [M][512] f32
template<int EPI>
__global__ __launch_bounds__(256, 2) void gemm128(const unsigned short* __restrict__ A,
                                                  const unsigned short* __restrict__ BT,
                                                  const float* __restrict__ bias,
                                                  void* __restrict__ outp) {
    __shared__ unsigned short lA[128 * 64];
    __shared__ unsigned short lB[128 * 64];
    const int tid = threadIdx.x;
    const int tile_n = blockIdx.x * 128;
    const int tile_m = blockIdx.y * 128;
    const int wid = tid >> 6, lane = tid & 63;
    const int wm = (wid >> 1) * 64, wn = (wid & 1) * 64;
    const int l16 = lane & 15, lg = lane >> 4;

    f32x4 acc[4][4];
#pragma unroll
    for (int i = 0; i < 4; ++i)
#pragma unroll
        for (int j = 0; j < 4; ++j)
            acc[i][j] = (f32x4){0.f, 0.f, 0.f, 0.f};

    const int r0 = tid >> 3;   // row of this thread's 16B chunk (i adds 32)
    const int cr = tid & 7;    // 16B chunk-in-row

    for (int kt = 0; kt < 512; kt += 64) {
#pragma unroll
        for (int i = 0; i < 4; ++i) {
            int r = r0 + i * 32;
            int crs = cr ^ (r & 7);  // pre-swizzled source so linear LDS + swizzled read works
            const unsigned short* ga = A + (size_t)(tile_m + r) * 512 + kt + crs * 8;
            const unsigned short* gb = BT + (size_t)(tile_n + r) * 512 + kt + crs * 8;
            __builtin_amdgcn_global_load_lds((const AS1 void*)ga, (AS3 void*)(&lA[(i * 256 + tid) * 8]), 16, 0, 0);
            __builtin_amdgcn_global_load_lds((const AS1 void*)gb, (AS3 void*)(&lB[(i * 256 + tid) * 8]), 16, 0, 0);
        }
        __syncthreads();
#pragma unroll
        for (int ks = 0; ks < 2; ++ks) {
            bf16x8 af[4], bfr[4];
#pragma unroll
            for (int f = 0; f < 4; ++f) {
                int ra = wm + f * 16 + l16;
                af[f] = *reinterpret_cast<const bf16x8*>(
                    reinterpret_cast<const char*>(lA) + ra * 128 + (((ks * 4 + lg) ^ (ra & 7)) << 4));
                int rb = wn + f * 16 + l16;
                bfr[f] = *reinterpret_cast<const bf16x8*>(
                    reinterpret_cast<const char*>(lB) + rb * 128 + (((ks * 4 + lg) ^ (rb & 7)) << 4));
            }
#pragma unroll
            for (int fm = 0; fm < 4; ++fm)
#pragma unroll
                for (int fn = 0; fn < 4; ++fn)
                    acc[fm][fn] = __builtin_amdgcn_mfma_f32_16x16x32_bf16(af[fm], bfr[fn], acc[fm][fn], 0, 0, 0);
        }
        __syncthreads();
    }

#pragma unroll
    for (int fm = 0; fm < 4; ++fm)
#pragma unroll
        for (int fn = 0; fn < 4; ++fn) {
            int gm0 = tile_m + wm + fm * 16 + lg * 4;
            int gn = tile_n + wn + fn * 16 + l16;
            float bs = bias[gn];
#pragma unroll
            for (int r = 0; r < 4; ++r) {
                float v = acc[fm][fn][r] + bs;
                int m = gm0 + r;
                if (EPI == 0) {
                    int b = m >> 11, s = m & 2047, h = gn >> 6, d = gn & 63;
                    ((unsigned short*)outp)[(((size_t)(b * 8 + h) * 2048 + s) << 6) + d] = f2bf(v);
                } else if (EPI == 1) {
                    int b = m >> 11, s = m & 2047, h = gn >> 6, d = gn & 63;
                    ((unsigned short*)outp)[(((size_t)(b * 8 + h) * 64 + d) << 11) + s] = f2bf(v);
                } else {
                    ((float*)outp)[(size_t)m * 512 + gn] = v;
                }
            }
        }
}

// ---------- causal flash attention ----------
// xb: [B][S][512] bf16 (Q = x), kb: [B][H][S][64], vT: [B][H][64][S], ob: [B][S][512]
__global__ __launch_bounds__(256, 4) void attn64(const unsigned short* __restrict__ xb,
                                                 const unsigned short* __restrict__ kb,
                                                 const unsigned short* __restrict__ vT,
                                                 unsigned short* __restrict__ ob) {
    __shared__ unsigned short plds_all[4][16][40];  // padded: stride 80B -> 2-way only
    const int tid = threadIdx.x;
    const int wid = tid >> 6, lane = tid & 63;
    const int l16 = lane & 15, lg = lane >> 4;
    const int bh = blockIdx.y;
    const int b = bh >> 3, h = bh & 7;
    const int qlo = blockIdx.x * 64 + wid * 16;

    unsigned short (*plds)[40] = plds_all[wid];

    bf16x8 qf0, qf1;
    {
        const unsigned short* qp = xb + (size_t)(b * 2048 + qlo + l16) * 512 + h * 64 + lg * 8;
        qf0 = *reinterpret_cast<const bf16x8*>(qp);
        qf1 = *reinterpret_cast<const bf16x8*>(qp + 32);
    }
    const unsigned short* Kb = kb + (size_t)bh * (2048 * 64);
    const unsigned short* Vb = vT + (size_t)bh * (64 * 2048);

    f32x4 o[4];
    float mrun[4], lrun[4];
#pragma unroll
    for (int i = 0; i < 4; ++i) o[i] = (f32x4){0.f, 0.f, 0.f, 0.f};
#pragma unroll
    for (int r = 0; r < 4; ++r) { mrun[r] = -1e30f; lrun[r] = 0.f; }

    const int qhi = qlo + 15;
    for (int kv = 0; kv <= qhi; kv += 32) {
        f32x4 s0 = (f32x4){0.f, 0.f, 0.f, 0.f}, s1 = (f32x4){0.f, 0.f, 0.f, 0.f};
        {
            const unsigned short* kp = Kb + (size_t)(kv + l16) * 64 + lg * 8;
            bf16x8 k0 = *reinterpret_cast<const bf16x8*>(kp);
            bf16x8 k1 = *reinterpret_cast<const bf16x8*>(kp + 32);
            s0 = __builtin_amdgcn_mfma_f32_16x16x32_bf16(qf0, k0, s0, 0, 0, 0);
            s0 = __builtin_amdgcn_mfma_f32_16x16x32_bf16(qf1, k1, s0, 0, 0, 0);
            kp += 16 * 64;
            bf16x8 k2 = *reinterpret_cast<const bf16x8*>(kp);
            bf16x8 k3 = *reinterpret_cast<const bf16x8*>(kp + 32);
            s1 = __builtin_amdgcn_mfma_f32_16x16x32_bf16(qf0, k2, s1, 0, 0, 0);
            s1 = __builtin_amdgcn_mfma_f32_16x16x32_bf16(qf1, k3, s1, 0, 0, 0);
        }
        const bool need_mask = (kv + 31 > qlo);
        float p0[4], p1[4], mt[4];
#pragma unroll
        for (int r = 0; r < 4; ++r) {
            float v0 = s0[r] * 0.125f;
            float v1 = s1[r] * 0.125f;
            if (need_mask) {
                int q = qlo + lg * 4 + r;
                if (kv + l16 > q) v0 = -1e30f;
                if (kv + 16 + l16 > q) v1 = -1e30f;
            }
            p0[r] = v0; p1[r] = v1;
            mt[r] = fmaxf(v0, v1);
        }
#pragma unroll
        for (int d = 1; d < 16; d <<= 1)
#pragma unroll
            for (int r = 0; r < 4; ++r)
                mt[r] = fmaxf(mt[r], __shfl_xor(mt[r], d, 64));
        float ls[4];
#pragma unroll
        for (int r = 0; r < 4; ++r) {
            float mn = fmaxf(mrun[r], mt[r]);
            float rs = __expf(mrun[r] - mn);
            mrun[r] = mn;
            p0[r] = __expf(p0[r] - mn);
            p1[r] = __expf(p1[r] - mn);
            ls[r] = p0[r] + p1[r];
            lrun[r] *= rs;
#pragma unroll
            for (int nb = 0; nb < 4; ++nb) o[nb][r] *= rs;
        }
#pragma unroll
        for (int d = 1; d < 16; d <<= 1)
#pragma unroll
            for (int r = 0; r < 4; ++r)
                ls[r] += __shfl_xor(ls[r], d, 64);
#pragma unroll
        for (int r = 0; r < 4; ++r) {
            lrun[r] += ls[r];
            plds[lg * 4 + r][l16] = f2bf(p0[r]);
            plds[lg * 4 + r][16 + l16] = f2bf(p1[r]);
        }
        bf16x8 pf = *reinterpret_cast<const bf16x8*>(&plds[l16][lg * 8]);
#pragma unroll
        for (int nb = 0; nb < 4; ++nb) {
            const unsigned short* vp = Vb + (size_t)(nb * 16 + l16) * 2048 + kv + lg * 8;
            bf16x8 vf = *reinterpret_cast<const bf16x8*>(vp);
            o[nb] = __builtin_amdgcn_mfma_f32_16x16x32_bf16(pf, vf, o[nb], 0, 0, 0);
        }
    }
#pragma unroll
    for (int r = 0; r < 4; ++r) lrun[r] = 1.f / lrun[r];
#pragma unroll
    for (int nb = 0; nb < 4; ++nb)
#pragma unroll
        for (int r = 0; r < 4; ++r) {
            int s = qlo + lg * 4 + r;
            ob[(size_t)(b * 2048 + s) * 512 + h * 64 + nb * 16 + l16] = f2bf(o[nb][r] * lrun[r]);
        }
}

extern "C" void kernel_launch(void* const* d_in, const int* in_sizes, int n_in,
                              void* d_out, int out_size, void* d_ws, size_t ws_size,
                              hipStream_t stream) {
    const float* x  = (const float*)d_in[0];
    const float* Wk = (const float*)d_in[1];
    const float* bk = (const float*)d_in[2];
    const float* Wv = (const float*)d_in[3];
    const float* bv = (const float*)d_in[4];
    const float* Wo = (const float*)d_in[5];
    const float* bo = (const float*)d_in[6];

    char* ws = (char*)d_ws;
    unsigned short* xb   = (unsigned short*)(ws);                    // 8 MB  [8192][512] bf16
    unsigned short* kbuf = (unsigned short*)(ws + (8ull << 20));     // 8 MB  [B][H][S][64]
    unsigned short* vTb  = (unsigned short*)(ws + (16ull << 20));    // 8 MB  [B][H][64][S]
    unsigned short* obuf = (unsigned short*)(ws + (24ull << 20));    // 8 MB  [8192][512]
    unsigned short* WkT  = (unsigned short*)(ws + (32ull << 20));    // 512 KB
    unsigned short* WvT  = (unsigned short*)(ws + (33ull << 20));    // 512 KB
    unsigned short* WoT  = (unsigned short*)(ws + (34ull << 20));    // 512 KB

    cvt_f32_bf16<<<4096, 256, 0, stream>>>(x, xb, 1048576);
    dim3 tg(16, 16), tb(32, 8);
    wtrans<<<tg, tb, 0, stream>>>(Wk, WkT);
    wtrans<<<tg, tb, 0, stream>>>(Wv, WvT);
    wtrans<<<tg, tb, 0, stream>>>(Wo, WoT);

    dim3 gg(4, 64);
    gemm128<0><<<gg, 256, 0, stream>>>(xb, WkT, bk, kbuf);
    gemm128<1><<<gg, 256, 0, stream>>>(xb, WvT, bv, vTb);

    attn64<<<dim3(32, 32), 256, 0, stream>>>(xb, kbuf, vTb, obuf);

    gemm128<2><<<gg, 256, 0, stream>>>(obuf, WoT, bo, d_out);
}

// Round 3
// 176.956 us; speedup vs baseline: 1.5701x; 1.5701x over previous
//
#include <hip/hip_runtime.h>
#include <stdint.h>
#include <stddef.h>

typedef short bf16x8 __attribute__((ext_vector_type(8)));
typedef float f32x4 __attribute__((ext_vector_type(4)));
typedef int i32x4 __attribute__((ext_vector_type(4)));

#define AS1 __attribute__((address_space(1)))
#define AS3 __attribute__((address_space(3)))

__device__ __forceinline__ unsigned short f2bf(float f) {
    union { float f; uint32_t u; } v; v.f = f;
    return (unsigned short)((v.u + 0x7fffu + ((v.u >> 16) & 1u)) >> 16);
}

// ---------- f32 -> bf16 convert (4 elems/thread) ----------
__global__ void cvt_f32_bf16(const float* __restrict__ in, unsigned short* __restrict__ out, int n4) {
    int i = blockIdx.x * blockDim.x + threadIdx.x;
    if (i >= n4) return;
    float4 v = reinterpret_cast<const float4*>(in)[i];
    ushort4 o;
    o.x = f2bf(v.x); o.y = f2bf(v.y); o.z = f2bf(v.z); o.w = f2bf(v.w);
    reinterpret_cast<ushort4*>(out)[i] = o;
}

// ---------- 512x512 transpose f32 -> bf16 : WT[n][k] = W[k][n] ----------
__global__ void wtrans(const float* __restrict__ W, unsigned short* __restrict__ WT) {
    __shared__ float tile[32][33];
    int bk = blockIdx.x * 32, bn = blockIdx.y * 32;
    int tx = threadIdx.x, ty = threadIdx.y;
#pragma unroll
    for (int r = 0; r < 32; r += 8)
        tile[ty + r][tx] = W[(size_t)(bk + ty + r) * 512 + bn + tx];
    __syncthreads();
#pragma unroll
    for (int r = 0; r < 32; r += 8)
        WT[(size_t)(bn + ty + r) * 512 + bk + tx] = f2bf(tile[tx][ty + r]);
}

// ---------- GEMM: C[M=8192][N=512] = A[M][512](bf16) * BT[N][512](bf16)^T + bias ----------
template<int EPI>
__global__ __launch_bounds__(256, 2) void gemm128(const unsigned short* __restrict__ A,
                                                  const unsigned short* __restrict__ BT,
                                                  const float* __restrict__ bias,
                                                  void* __restrict__ outp) {
    __shared__ unsigned short lA[128 * 64];
    __shared__ unsigned short lB[128 * 64];
    const int tid = threadIdx.x;
    const int tile_n = blockIdx.x * 128;
    const int tile_m = blockIdx.y * 128;
    const int wid = tid >> 6, lane = tid & 63;
    const int wm = (wid >> 1) * 64, wn = (wid & 1) * 64;
    const int l16 = lane & 15, lg = lane >> 4;

    f32x4 acc[4][4];
#pragma unroll
    for (int i = 0; i < 4; ++i)
#pragma unroll
        for (int j = 0; j < 4; ++j)
            acc[i][j] = (f32x4){0.f, 0.f, 0.f, 0.f};

    const int r0 = tid >> 3;
    const int cr = tid & 7;

    for (int kt = 0; kt < 512; kt += 64) {
#pragma unroll
        for (int i = 0; i < 4; ++i) {
            int r = r0 + i * 32;
            int crs = cr ^ (r & 7);
            const unsigned short* ga = A + (size_t)(tile_m + r) * 512 + kt + crs * 8;
            const unsigned short* gb = BT + (size_t)(tile_n + r) * 512 + kt + crs * 8;
            __builtin_amdgcn_global_load_lds((const AS1 void*)ga, (AS3 void*)(&lA[(i * 256 + tid) * 8]), 16, 0, 0);
            __builtin_amdgcn_global_load_lds((const AS1 void*)gb, (AS3 void*)(&lB[(i * 256 + tid) * 8]), 16, 0, 0);
        }
        __syncthreads();
#pragma unroll
        for (int ks = 0; ks < 2; ++ks) {
            bf16x8 af[4], bfr[4];
#pragma unroll
            for (int f = 0; f < 4; ++f) {
                int ra = wm + f * 16 + l16;
                af[f] = *reinterpret_cast<const bf16x8*>(
                    reinterpret_cast<const char*>(lA) + ra * 128 + (((ks * 4 + lg) ^ (ra & 7)) << 4));
                int rb = wn + f * 16 + l16;
                bfr[f] = *reinterpret_cast<const bf16x8*>(
                    reinterpret_cast<const char*>(lB) + rb * 128 + (((ks * 4 + lg) ^ (rb & 7)) << 4));
            }
#pragma unroll
            for (int fm = 0; fm < 4; ++fm)
#pragma unroll
                for (int fn = 0; fn < 4; ++fn)
                    acc[fm][fn] = __builtin_amdgcn_mfma_f32_16x16x32_bf16(af[fm], bfr[fn], acc[fm][fn], 0, 0, 0);
        }
        __syncthreads();
    }

#pragma unroll
    for (int fm = 0; fm < 4; ++fm)
#pragma unroll
        for (int fn = 0; fn < 4; ++fn) {
            int gm0 = tile_m + wm + fm * 16 + lg * 4;
            int gn = tile_n + wn + fn * 16 + l16;
            float bs = bias[gn];
#pragma unroll
            for (int r = 0; r < 4; ++r) {
                float v = acc[fm][fn][r] + bs;
                int m = gm0 + r;
                if (EPI == 0) {
                    int b = m >> 11, s = m & 2047, h = gn >> 6, d = gn & 63;
                    ((unsigned short*)outp)[(((size_t)(b * 8 + h) * 2048 + s) << 6) + d] = f2bf(v);
                } else if (EPI == 1) {
                    int b = m >> 11, s = m & 2047, h = gn >> 6, d = gn & 63;
                    ((unsigned short*)outp)[(((size_t)(b * 8 + h) * 64 + d) << 11) + s] = f2bf(v);
                } else {
                    ((float*)outp)[(size_t)m * 512 + gn] = v;
                }
            }
        }
}

// ---------- causal flash attention, transposed-QK (lane-local softmax) ----------
// Each wave owns 16 q-rows. S^T = mfma(K_perm, Q) so lane (lg,l16) holds
// scores for q = qlo+l16, k = kv + 8*lg + {0..7} -> exactly the PV A-operand
// kk-layout. No LDS, no P shuffles. Defer-max (THR=8) skips o-rescale.
// Block = 2 waves with q-groups (g, 127-g) -> flat work per block.
__global__ __launch_bounds__(128, 4) void attn_t(const unsigned short* __restrict__ xq,
                                                 const unsigned short* __restrict__ kg,
                                                 const unsigned short* __restrict__ vT,
                                                 unsigned short* __restrict__ ob) {
    const int lane = threadIdx.x & 63;
    const int wid = threadIdx.x >> 6;
    const int l16 = lane & 15, lg = lane >> 4;
    const int bh = blockIdx.y, b = bh >> 3, h = bh & 7;
    const int g = wid ? (127 - blockIdx.x) : blockIdx.x;
    const int qlo = g * 16;
    const int q = qlo + l16;

    const unsigned short* qp = xq + ((size_t)(b * 2048 + qlo + l16) * 512) + h * 64 + lg * 8;
    bf16x8 qf0 = *(const bf16x8*)qp;
    bf16x8 qf1 = *(const bf16x8*)(qp + 32);

    const unsigned short* Kb = kg + (size_t)bh * (2048 * 64);
    const unsigned short* Vb = vT + (size_t)bh * (64 * 2048);
    // permuted K row within tile: sigma_s(l16) = 8*(l16>>2) + 4*s + (l16&3)
    const unsigned short* kbase = Kb + (size_t)(8 * (l16 >> 2) + (l16 & 3)) * 64 + lg * 8;
    const unsigned short* vbase = Vb + (size_t)l16 * 2048 + lg * 8;

    f32x4 o[4];
#pragma unroll
    for (int i = 0; i < 4; ++i) o[i] = (f32x4){0.f, 0.f, 0.f, 0.f};
    float mrun = -1e30f, lrun = 0.f;

    const int nt = ((qlo + 15) >> 5) + 1;

    bf16x8 kA00, kA01, kA10, kA11, kB00, kB01, kB10, kB11;

#define LOADK(P, KV) { \
        const unsigned short* kp_ = kbase + (size_t)(KV) * 64; \
        P##00 = *(const bf16x8*)kp_;          P##01 = *(const bf16x8*)(kp_ + 32); \
        P##10 = *(const bf16x8*)(kp_ + 256);  P##11 = *(const bf16x8*)(kp_ + 256 + 32); }

#define BODY(P, KV) { \
        const unsigned short* vp_ = vbase + (KV); \
        bf16x8 vf0 = *(const bf16x8*)(vp_); \
        bf16x8 vf1 = *(const bf16x8*)(vp_ + 16 * 2048); \
        bf16x8 vf2 = *(const bf16x8*)(vp_ + 32 * 2048); \
        bf16x8 vf3 = *(const bf16x8*)(vp_ + 48 * 2048); \
        f32x4 sA = (f32x4){0.f,0.f,0.f,0.f}, sB = (f32x4){0.f,0.f,0.f,0.f}; \
        sA = __builtin_amdgcn_mfma_f32_16x16x32_bf16(P##00, qf0, sA, 0, 0, 0); \
        sA = __builtin_amdgcn_mfma_f32_16x16x32_bf16(P##01, qf1, sA, 0, 0, 0); \
        sB = __builtin_amdgcn_mfma_f32_16x16x32_bf16(P##10, qf0, sB, 0, 0, 0); \
        sB = __builtin_amdgcn_mfma_f32_16x16x32_bf16(P##11, qf1, sB, 0, 0, 0); \
        float p0[4], p1[4]; \
        const bool nm = ((KV) + 31 > qlo); \
        _Pragma("unroll") \
        for (int r = 0; r < 4; ++r) { \
            float a = sA[r] * 0.125f, c = sB[r] * 0.125f; \
            if (nm) { \
                int kidx = (KV) + 8 * lg + r; \
                if (kidx > q) a = -1e30f; \
                if (kidx + 4 > q) c = -1e30f; \
            } \
            p0[r] = a; p1[r] = c; \
        } \
        float mt = fmaxf(fmaxf(fmaxf(p0[0], p0[1]), fmaxf(p0[2], p0[3])), \
                         fmaxf(fmaxf(p1[0], p1[1]), fmaxf(p1[2], p1[3]))); \
        mt = fmaxf(mt, __shfl_xor(mt, 16, 64)); \
        mt = fmaxf(mt, __shfl_xor(mt, 32, 64)); \
        if (!__all(mt <= mrun + 8.0f)) { \
            float mn = fmaxf(mrun, mt); \
            float rs = __expf(mrun - mn); \
            mrun = mn; lrun *= rs; \
            float rr0 = __shfl(rs, 4 * lg + 0, 64); \
            float rr1 = __shfl(rs, 4 * lg + 1, 64); \
            float rr2 = __shfl(rs, 4 * lg + 2, 64); \
            float rr3 = __shfl(rs, 4 * lg + 3, 64); \
            _Pragma("unroll") \
            for (int nb = 0; nb < 4; ++nb) { \
                o[nb][0] *= rr0; o[nb][1] *= rr1; o[nb][2] *= rr2; o[nb][3] *= rr3; \
            } \
        } \
        _Pragma("unroll") \
        for (int r = 0; r < 4; ++r) { \
            p0[r] = __expf(p0[r] - mrun); \
            p1[r] = __expf(p1[r] - mrun); \
        } \
        float ls = (p0[0] + p0[1]) + (p0[2] + p0[3]) + (p1[0] + p1[1]) + (p1[2] + p1[3]); \
        ls += __shfl_xor(ls, 16, 64); \
        ls += __shfl_xor(ls, 32, 64); \
        lrun += ls; \
        uint32_t u0, u1, u2, u3; \
        asm("v_cvt_pk_bf16_f32 %0, %1, %2" : "=v"(u0) : "v"(p0[0]), "v"(p0[1])); \
        asm("v_cvt_pk_bf16_f32 %0, %1, %2" : "=v"(u1) : "v"(p0[2]), "v"(p0[3])); \
        asm("v_cvt_pk_bf16_f32 %0, %1, %2" : "=v"(u2) : "v"(p1[0]), "v"(p1[1])); \
        asm("v_cvt_pk_bf16_f32 %0, %1, %2" : "=v"(u3) : "v"(p1[2]), "v"(p1[3])); \
        union { i32x4 i; bf16x8 h; } pu; \
        pu.i = (i32x4){(int)u0, (int)u1, (int)u2, (int)u3}; \
        o[0] = __builtin_amdgcn_mfma_f32_16x16x32_bf16(pu.h, vf0, o[0], 0, 0, 0); \
        o[1] = __builtin_amdgcn_mfma_f32_16x16x32_bf16(pu.h, vf1, o[1], 0, 0, 0); \
        o[2] = __builtin_amdgcn_mfma_f32_16x16x32_bf16(pu.h, vf2, o[2], 0, 0, 0); \
        o[3] = __builtin_amdgcn_mfma_f32_16x16x32_bf16(pu.h, vf3, o[3], 0, 0, 0); }

    int t = 0;
    LOADK(kA, 0);
    for (;;) {
        if (t + 1 < nt) LOADK(kB, (t + 1) << 5);
        BODY(kA, (t << 5));
        if (++t >= nt) break;
        if (t + 1 < nt) LOADK(kA, (t + 1) << 5);
        BODY(kB, (t << 5));
        if (++t >= nt) break;
    }
#undef LOADK
#undef BODY

    float linv[4];
#pragma unroll
    for (int r = 0; r < 4; ++r)
        linv[r] = 1.f / __shfl(lrun, 4 * lg + r, 64);
#pragma unroll
    for (int nb = 0; nb < 4; ++nb)
#pragma unroll
        for (int r = 0; r < 4; ++r) {
            int s = qlo + 4 * lg + r;
            ob[(size_t)(b * 2048 + s) * 512 + h * 64 + nb * 16 + l16] = f2bf(o[nb][r] * linv[r]);
        }
}

extern "C" void kernel_launch(void* const* d_in, const int* in_sizes, int n_in,
                              void* d_out, int out_size, void* d_ws, size_t ws_size,
                              hipStream_t stream) {
    const float* x  = (const float*)d_in[0];
    const float* Wk = (const float*)d_in[1];
    const float* bk = (const float*)d_in[2];
    const float* Wv = (const float*)d_in[3];
    const float* bv = (const float*)d_in[4];
    const float* Wo = (const float*)d_in[5];
    const float* bo = (const float*)d_in[6];

    char* ws = (char*)d_ws;
    unsigned short* xb   = (unsigned short*)(ws);                    // 8 MB  [8192][512] bf16
    unsigned short* kbuf = (unsigned short*)(ws + (8ull << 20));     // 8 MB  [B][H][S][64]
    unsigned short* vTb  = (unsigned short*)(ws + (16ull << 20));    // 8 MB  [B][H][64][S]
    unsigned short* obuf = (unsigned short*)(ws + (24ull << 20));    // 8 MB  [8192][512]
    unsigned short* WkT  = (unsigned short*)(ws + (32ull << 20));    // 512 KB
    unsigned short* WvT  = (unsigned short*)(ws + (33ull << 20));    // 512 KB
    unsigned short* WoT  = (unsigned short*)(ws + (34ull << 20));    // 512 KB

    cvt_f32_bf16<<<4096, 256, 0, stream>>>(x, xb, 1048576);
    dim3 tg(16, 16), tb(32, 8);
    wtrans<<<tg, tb, 0, stream>>>(Wk, WkT);
    wtrans<<<tg, tb, 0, stream>>>(Wv, WvT);
    wtrans<<<tg, tb, 0, stream>>>(Wo, WoT);

    dim3 gg(4, 64);
    gemm128<0><<<gg, 256, 0, stream>>>(xb, WkT, bk, kbuf);
    gemm128<1><<<gg, 256, 0, stream>>>(xb, WvT, bv, vTb);

    attn_t<<<dim3(64, 32), 128, 0, stream>>>(xb, kbuf, vTb, obuf);

    gemm128<2><<<gg, 256, 0, stream>>>(obuf, WoT, bo, d_out);
}